// Round 2
// 908.570 us; speedup vs baseline: 1.2434x; 1.2434x over previous
//
#include <hip/hip_runtime.h>

typedef __attribute__((ext_vector_type(8))) short bf16x8;
typedef __attribute__((ext_vector_type(4))) float f32x4;

__device__ __forceinline__ float b2f(ushort u) {
    union { unsigned int i; float f; } v; v.i = ((unsigned int)u) << 16; return v.f;
}
__device__ __forceinline__ ushort f2b(float f) {
    union { float f; unsigned int i; } v; v.f = f;
    unsigned int i = v.i;
    return (ushort)((i + 0x7FFFu + ((i >> 16) & 1u)) >> 16);
}
__device__ __forceinline__ void glds16(const ushort* g, ushort* l) {
    __builtin_amdgcn_global_load_lds((const __attribute__((address_space(1))) void*)g,
                                     (__attribute__((address_space(3))) void*)l, 16, 0, 0);
}
// raw barrier with compiler memory fences (no implicit vmcnt/lgkm drain)
__device__ __forceinline__ void BARX() {
    asm volatile("" ::: "memory");
    __builtin_amdgcn_s_barrier();
    asm volatile("" ::: "memory");
}

// ---- LN2: x2(fp32 rows,1024) -> y (bf16) ----
__global__ __launch_bounds__(256) void ln_kernel(const float* __restrict__ x,
                                                 const float* __restrict__ sc,
                                                 const float* __restrict__ bi,
                                                 ushort* __restrict__ y) {
    __shared__ float red[8];
    long row = blockIdx.x;
    const float* xr = x + row * 1024;
    int t = threadIdx.x;
    float4 u = *(const float4*)(xr + t * 4);
    float s = u.x + u.y + u.z + u.w;
    float q = u.x * u.x + u.y * u.y + u.z * u.z + u.w * u.w;
    for (int off = 32; off > 0; off >>= 1) {
        s += __shfl_xor(s, off);
        q += __shfl_xor(q, off);
    }
    if ((t & 63) == 0) { red[t >> 6] = s; red[4 + (t >> 6)] = q; }
    __syncthreads();
    s = red[0] + red[1] + red[2] + red[3];
    q = red[4] + red[5] + red[6] + red[7];
    float mean = s * (1.0f / 1024.0f);
    float var = q * (1.0f / 1024.0f) - mean * mean;
    float rstd = rsqrtf(fmaxf(var, 0.0f) + 1e-6f);
    int c = t * 4;
    float o0 = (u.x - mean) * rstd * sc[c + 0] + bi[c + 0];
    float o1 = (u.y - mean) * rstd * sc[c + 1] + bi[c + 1];
    float o2 = (u.z - mean) * rstd * sc[c + 2] + bi[c + 2];
    float o3 = (u.w - mean) * rstd * sc[c + 3] + bi[c + 3];
    uint2 o;
    o.x = (unsigned int)f2b(o0) | ((unsigned int)f2b(o1) << 16);
    o.y = (unsigned int)f2b(o2) | ((unsigned int)f2b(o3) << 16);
    *(uint2*)(y + row * 1024 + c) = o;
}

// ---- fused LN1 + window partition ----
__global__ __launch_bounds__(256) void ln_part_kernel(const float* __restrict__ x,
                                                      const float* __restrict__ sc,
                                                      const float* __restrict__ bi,
                                                      ushort* __restrict__ wy,
                                                      int win_base, int nvalid) {
    __shared__ float red[8];
    int wt = blockIdx.x;
    int lwin = wt / 196, rr = wt % 196;
    int t = threadIdx.x;
    int valid = 0;
    long xrow = 0;
    if (lwin < nvalid) {
        int gwin = win_base + lwin;
        int img = gwin / 25, wrem = gwin % 25;
        int gh = (wrem / 5) * 14 + rr / 14;
        int gw = (wrem % 5) * 14 + rr % 14;
        if (gh < 64 && gw < 64) {
            valid = 1;
            xrow = (long)img * 4096 + gh * 64 + gw;
        }
    }
    uint2 o; o.x = 0u; o.y = 0u;
    if (valid) {
        const float* xr = x + xrow * 1024;
        float4 u = *(const float4*)(xr + t * 4);
        float s = u.x + u.y + u.z + u.w;
        float q = u.x * u.x + u.y * u.y + u.z * u.z + u.w * u.w;
        for (int off = 32; off > 0; off >>= 1) {
            s += __shfl_xor(s, off);
            q += __shfl_xor(q, off);
        }
        if ((t & 63) == 0) { red[t >> 6] = s; red[4 + (t >> 6)] = q; }
        __syncthreads();
        s = red[0] + red[1] + red[2] + red[3];
        q = red[4] + red[5] + red[6] + red[7];
        float mean = s * (1.0f / 1024.0f);
        float var = q * (1.0f / 1024.0f) - mean * mean;
        float rstd = rsqrtf(fmaxf(var, 0.0f) + 1e-6f);
        int c = t * 4;
        float o0 = (u.x - mean) * rstd * sc[c + 0] + bi[c + 0];
        float o1 = (u.y - mean) * rstd * sc[c + 1] + bi[c + 1];
        float o2 = (u.z - mean) * rstd * sc[c + 2] + bi[c + 2];
        float o3 = (u.w - mean) * rstd * sc[c + 3] + bi[c + 3];
        o.x = (unsigned int)f2b(o0) | ((unsigned int)f2b(o1) << 16);
        o.y = (unsigned int)f2b(o2) | ((unsigned int)f2b(o3) << 16);
    }
    *(uint2*)(wy + (long)wt * 1024 + t * 4) = o;
}

// ---- transpose + cast: in fp32 (K,N) -> out bf16 (N,K) ----
__global__ void transpose_w(const float* __restrict__ in, ushort* __restrict__ out,
                            int K, int N) {
    __shared__ float tile[32][33];
    int n0 = blockIdx.x * 32, k0 = blockIdx.y * 32;
    int tx = threadIdx.x, ty = threadIdx.y;
    for (int i = 0; i < 32; i += 8)
        tile[ty + i][tx] = in[(long)(k0 + ty + i) * N + n0 + tx];
    __syncthreads();
    for (int i = 0; i < 32; i += 8)
        out[(long)(n0 + ty + i) * K + k0 + tx] = f2b(tile[tx][ty + i]);
}

// ---- legacy GEMM (m97 structure, proven) ----
template <int FLAGS, typename OT>
__global__ __launch_bounds__(256) void gemm_bt(const ushort* __restrict__ A,
                                               const ushort* __restrict__ Bt,
                                               const float* __restrict__ bias,
                                               const float* __restrict__ resid,
                                               OT* __restrict__ out,
                                               int M, int N, int K) {
    __shared__ __align__(16) ushort As[128 * 32];
    __shared__ __align__(16) ushort Bs[128 * 32];
    const int tid = threadIdx.x;
    const int lane = tid & 63, w = tid >> 6;
    const int wm = (w >> 1) * 64, wn = (w & 1) * 64;
    const int quad = lane >> 4, l16 = lane & 15;
    const int bm = blockIdx.x * 128, bn = blockIdx.y * 128;
    const int r = tid >> 2, kc = (tid & 3) * 8;
    f32x4 acc[4][4];
#pragma unroll
    for (int i = 0; i < 4; i++)
#pragma unroll
        for (int j = 0; j < 4; j++) acc[i][j] = (f32x4){0.f, 0.f, 0.f, 0.f};
    const ushort* Ag = A + (long)(bm + r) * K + kc;
    const ushort* Bg = Bt + (long)(bn + r) * K + kc;
    ushort* AsW = As + w * 512;
    ushort* BsW = Bs + w * 512;
    for (int k0 = 0; k0 < K; k0 += 32) {
        __syncthreads();
        glds16(Ag + k0, AsW);
        glds16(Ag + (long)64 * K + k0, AsW + 2048);
        glds16(Bg + k0, BsW);
        glds16(Bg + (long)64 * K + k0, BsW + 2048);
        __syncthreads();
        bf16x8 afr[4], bfr[4];
#pragma unroll
        for (int t = 0; t < 4; t++) {
            afr[t] = *(const bf16x8*)&As[(wm + t * 16 + l16) * 32 + quad * 8];
            bfr[t] = *(const bf16x8*)&Bs[(wn + t * 16 + l16) * 32 + quad * 8];
        }
#pragma unroll
        for (int tm = 0; tm < 4; tm++)
#pragma unroll
            for (int tn = 0; tn < 4; tn++)
                acc[tm][tn] = __builtin_amdgcn_mfma_f32_16x16x32_bf16(afr[tm], bfr[tn],
                                                                     acc[tm][tn], 0, 0, 0);
    }
#pragma unroll
    for (int tm = 0; tm < 4; tm++) {
#pragma unroll
        for (int j = 0; j < 4; j++) {
            int gm = bm + wm + tm * 16 + quad * 4 + j;
#pragma unroll
            for (int tn = 0; tn < 4; tn++) {
                int gn = bn + wn + tn * 16 + l16;
                float v = acc[tm][tn][j] + bias[gn];
                if (FLAGS & 1) v = 0.5f * v * (1.0f + erff(v * 0.70710678118654752f));
                if (FLAGS & 2) v += resid[(long)gm * N + gn];
                if (sizeof(OT) == 4) out[(long)gm * N + gn] = (OT)v;
                else out[(long)gm * N + gn] = (OT)f2b(v);
            }
        }
    }
}

// ================= 256x256 deep-pipelined GEMM (8-phase-template port) =================
// BM=BN=256, BK=32, 4-deep LDS ring (128 KiB), 8 waves (2Mx4N), 512 threads.
// Per K-tile: 2 phases x 16 MFMA; half-tile staged per phase via global_load_lds;
// counted s_waitcnt vmcnt(8) once per K-tile (tail 8->4->0), never 0 in main loop.
// LDS XOR-swizzle (slot ^= row&3) applied on the pre-swizzled GLOBAL source column
// and on the asm ds_read address (rule 21: both-sides-or-neither).
// asm ds_read + lgkmcnt(0) + sched_barrier(0) per rule 18; sched_barrier(0) after
// each staging group pins global_load_lds issue order for the vmcnt bookkeeping.
#define DSR(dst, addr, imm) \
    asm volatile("ds_read_b128 %0, %1 offset:%2" : "=&v"(dst) : "v"(addr), "n"(imm));

#define MF1(m, n, ar, br) \
    acc[m][n] = __builtin_amdgcn_mfma_f32_16x16x32_bf16(ar, br, acc[m][n], 0, 0, 0);
#define MFROW(m, ar) MF1(m, 0, ar, vb0) MF1(m, 1, ar, vb1) MF1(m, 2, ar, vb2) MF1(m, 3, ar, vb3)

#define SEG(bb, ts, STG, VM) do {                                                        \
    bf16x8 vb0, vb1, vb2, vb3, va0, va1, va2, va3;                                       \
    DSR(vb0, b_addr, (bb) * 16384 + 0)                                                   \
    DSR(vb1, b_addr, (bb) * 16384 + 1024)                                                \
    DSR(vb2, b_addr, (bb) * 16384 + 2048)                                                \
    DSR(vb3, b_addr, (bb) * 16384 + 3072)                                                \
    DSR(va0, a_addr, (bb) * 16384 + 0)                                                   \
    DSR(va1, a_addr, (bb) * 16384 + 1024)                                                \
    DSR(va2, a_addr, (bb) * 16384 + 2048)                                                \
    DSR(va3, a_addr, (bb) * 16384 + 3072)                                                \
    if (STG) {                                                                           \
        glds16(Ag + (long)(ts) * 32, &As[((bb) + 3) & 3][sdst]);                         \
        glds16(Ag2 + (long)(ts) * 32, &As[((bb) + 3) & 3][sdst + 4096]);                 \
        __builtin_amdgcn_sched_barrier(0);                                               \
    }                                                                                    \
    BARX();                                                                              \
    asm volatile("s_waitcnt lgkmcnt(0)" ::: "memory");                                   \
    __builtin_amdgcn_sched_barrier(0);                                                   \
    __builtin_amdgcn_s_setprio(1);                                                       \
    MFROW(0, va0) MFROW(1, va1) MFROW(2, va2) MFROW(3, va3)                              \
    __builtin_amdgcn_s_setprio(0);                                                       \
    BARX();                                                                              \
    DSR(va0, a_addr, (bb) * 16384 + 4096)                                                \
    DSR(va1, a_addr, (bb) * 16384 + 5120)                                                \
    DSR(va2, a_addr, (bb) * 16384 + 6144)                                                \
    DSR(va3, a_addr, (bb) * 16384 + 7168)                                                \
    if (STG) {                                                                           \
        glds16(Bg + (long)(ts) * 32, &Bs[((bb) + 3) & 3][sdst]);                         \
        glds16(Bg2 + (long)(ts) * 32, &Bs[((bb) + 3) & 3][sdst + 4096]);                 \
        __builtin_amdgcn_sched_barrier(0);                                               \
    }                                                                                    \
    BARX();                                                                              \
    asm volatile("s_waitcnt lgkmcnt(0)" ::: "memory");                                   \
    __builtin_amdgcn_sched_barrier(0);                                                   \
    __builtin_amdgcn_s_setprio(1);                                                       \
    MFROW(4, va0) MFROW(5, va1) MFROW(6, va2) MFROW(7, va3)                              \
    __builtin_amdgcn_s_setprio(0);                                                       \
    __builtin_amdgcn_sched_barrier(0);                                                   \
    asm volatile("s_waitcnt " VM ::: "memory");                                          \
    BARX();                                                                              \
} while (0)

template <int FLAGS, typename OT>
__global__ __launch_bounds__(512, 2) void gemm256(const ushort* __restrict__ A,
                                                  const ushort* __restrict__ Bt,
                                                  const float* __restrict__ bias,
                                                  const float* __restrict__ resid,
                                                  OT* __restrict__ out,
                                                  int M, int N, int K, int nbn) {
    __shared__ __align__(64) ushort As[4][8192];   // 4 x (256 rows x 32 halfs) = 64 KB
    __shared__ __align__(64) ushort Bs[4][8192];   // 64 KB
    // bijective XCD swizzle (m204)
    const int nwg = gridDim.x;
    const int orig = blockIdx.x;
    const int q8 = nwg >> 3, r8 = nwg & 7;
    const int xcd = orig & 7, sub = orig >> 3;
    const int wgid = (xcd < r8 ? xcd * (q8 + 1) : r8 * (q8 + 1) + (xcd - r8) * q8) + sub;
    const int bm = (wgid / nbn) * 256, bn = (wgid % nbn) * 256;

    const int tid = threadIdx.x;
    const int lane = tid & 63, w = tid >> 6;
    const int quad = lane >> 4, l16 = lane & 15;
    const int wm = (w >> 2) * 128, wn = (w & 3) * 64;

    // staging: per glds issue a wave writes 16 rows x 64B linearly; source column
    // is pre-swizzled (slot ^ row&3) so LDS content is swizzled (rule 21).
    const int r_st = w * 16 + (lane >> 2);                     // 0..127
    const int c_st = (((lane & 3) ^ ((lane >> 2) & 3)) << 3);  // halfs
    const ushort* Ag = A + (long)(bm + r_st) * K + c_st;
    const ushort* Ag2 = Ag + (long)128 * K;
    const ushort* Bg = Bt + (long)(bn + r_st) * K + c_st;
    const ushort* Bg2 = Bg + (long)128 * K;
    const int sdst = w * 512;                                  // halfs

    // read addresses (byte): frag m at +m*1024, ring buffer b at +b*16384
    const int a_base = (wm + l16) * 32 + ((quad ^ (l16 & 3)) << 3);
    const int b_base = (wn + l16) * 32 + ((quad ^ (l16 & 3)) << 3);
    const unsigned a_addr =
        (unsigned)(size_t)(__attribute__((address_space(3))) ushort*)&As[0][0] +
        (unsigned)(a_base * 2);
    const unsigned b_addr =
        (unsigned)(size_t)(__attribute__((address_space(3))) ushort*)&Bs[0][0] +
        (unsigned)(b_base * 2);

    f32x4 acc[8][4];
#pragma unroll
    for (int i = 0; i < 8; i++)
#pragma unroll
        for (int j = 0; j < 4; j++) acc[i][j] = (f32x4){0.f, 0.f, 0.f, 0.f};

    // prologue: stage K-tiles 0,1,2 into buffers 0,1,2 (12 loads), keep 2 in flight
    glds16(Ag, &As[0][sdst]);       glds16(Ag2, &As[0][sdst + 4096]);
    glds16(Bg, &Bs[0][sdst]);       glds16(Bg2, &Bs[0][sdst + 4096]);
    glds16(Ag + 32, &As[1][sdst]);  glds16(Ag2 + 32, &As[1][sdst + 4096]);
    glds16(Bg + 32, &Bs[1][sdst]);  glds16(Bg2 + 32, &Bs[1][sdst + 4096]);
    glds16(Ag + 64, &As[2][sdst]);  glds16(Ag2 + 64, &As[2][sdst + 4096]);
    glds16(Bg + 64, &Bs[2][sdst]);  glds16(Bg2 + 64, &Bs[2][sdst + 4096]);
    __builtin_amdgcn_sched_barrier(0);
    asm volatile("s_waitcnt vmcnt(8)" ::: "memory");  // tile 0 landed
    BARX();

    const int nt = K >> 5;  // 32 (K=1024) or 128 (K=4096); divisible by 4, >= 8
    for (int t = 0; t < nt - 4; t += 4) {
        SEG(0, t + 3, 1, "vmcnt(8)");
        SEG(1, t + 4, 1, "vmcnt(8)");
        SEG(2, t + 5, 1, "vmcnt(8)");
        SEG(3, t + 6, 1, "vmcnt(8)");
    }
    // peeled tail: tiles nt-4..nt-1; stage last tile (nt-1); drain 8 -> 4 -> 0
    SEG(0, nt - 1, 1, "vmcnt(8)");
    SEG(1, 0, 0, "vmcnt(4)");
    SEG(2, 0, 0, "vmcnt(0)");
    SEG(3, 0, 0, "vmcnt(0)");

    // epilogue
#pragma unroll
    for (int m = 0; m < 8; m++) {
#pragma unroll
        for (int j = 0; j < 4; j++) {
            const int gm = bm + wm + m * 16 + quad * 4 + j;
            const long ro = (long)gm * N;
#pragma unroll
            for (int n = 0; n < 4; n++) {
                const int gn = bn + wn + n * 16 + l16;
                float v = acc[m][n][j] + bias[gn];
                if (FLAGS & 1) v = 0.5f * v * (1.0f + erff(v * 0.70710678118654752f));
                if (FLAGS & 2) v += resid[ro + gn];
                if (sizeof(OT) == 4) out[ro + gn] = (OT)v;
                else out[ro + gn] = (OT)f2b(v);
            }
        }
    }
}

// ---- attention per (window, head): rel-pos via MFMA, 46 KB LDS ----
__global__ __launch_bounds__(256) void attn_kernel(const ushort* __restrict__ qkv,
                                                   ushort* __restrict__ o_out,
                                                   const float* __restrict__ relH,
                                                   const float* __restrict__ relW,
                                                   int win0, long orow0) {
    __shared__ __align__(16) ushort Vt[64 * 200];
    __shared__ __align__(16) ushort Ps[64 * 104];
    __shared__ __align__(16) ushort sc[8 * 448];
    const int head = blockIdx.y;
    const long qbase = (long)blockIdx.x * 196 * 3072 + head * 64;
    const int gwin = win0 + blockIdx.x;
    const int img = gwin / 25, wrem = gwin % 25;
    const int whh = (wrem / 5) * 14, www = (wrem % 5) * 14;
    const int tid = threadIdx.x, lane = tid & 63, w = tid >> 6;
    const int quad = lane >> 4, l16 = lane & 15;

    for (int idx = tid; idx < 196 * 64; idx += 256) {
        int k = idx >> 6, d = idx & 63;
        Vt[d * 200 + k] = qkv[qbase + 2048 + (long)k * 3072 + d];
    }
    __syncthreads();

    bf16x8 bH[2][2], bW[2][2];
#pragma unroll
    for (int nt = 0; nt < 2; nt++) {
        int n = nt * 16 + l16;
#pragma unroll
        for (int kt = 0; kt < 2; kt++) {
            bf16x8 rh = (bf16x8){0, 0, 0, 0, 0, 0, 0, 0};
            bf16x8 rw = (bf16x8){0, 0, 0, 0, 0, 0, 0, 0};
            if (n < 27) {
                const float* ph = relH + n * 64 + kt * 32 + quad * 8;
                const float* pw = relW + n * 64 + kt * 32 + quad * 8;
#pragma unroll
                for (int e = 0; e < 8; e++) {
                    rh[e] = (short)f2b(ph[e]);
                    rw[e] = (short)f2b(pw[e]);
                }
            }
            bH[nt][kt] = rh;
            bW[nt][kt] = rw;
        }
    }

    for (int tr = w; tr < 13; tr += 4) {
        int qrow = tr * 16 + l16;
        if (qrow > 195) qrow = 195;
        bf16x8 qf0 = *(const bf16x8*)(qkv + qbase + (long)qrow * 3072 + quad * 8);
        bf16x8 qf1 = *(const bf16x8*)(qkv + qbase + (long)qrow * 3072 + 32 + quad * 8);

#pragma unroll
        for (int tab = 0; tab < 2; tab++) {
#pragma unroll
            for (int nt = 0; nt < 2; nt++) {
                f32x4 a = (f32x4){0.f, 0.f, 0.f, 0.f};
                a = __builtin_amdgcn_mfma_f32_16x16x32_bf16(qf0, tab ? bW[nt][0] : bH[nt][0],
                                                            a, 0, 0, 0);
                a = __builtin_amdgcn_mfma_f32_16x16x32_bf16(qf1, tab ? bW[nt][1] : bH[nt][1],
                                                            a, 0, 0, 0);
                int col = nt * 16 + l16;
                if (col < 27) {
#pragma unroll
                    for (int j = 0; j < 4; j++)
                        sc[(w * 2 + tab) * 448 + (quad * 4 + j) * 28 + col] = f2b(a[j]);
                }
            }
        }

        f32x4 sf[13];
#pragma unroll
        for (int tc = 0; tc < 13; tc++) {
            int krow = tc * 16 + l16;
            if (krow > 195) krow = 195;
            const ushort* kp = qkv + qbase + 1024 + (long)krow * 3072 + quad * 8;
            bf16x8 kf0 = *(const bf16x8*)kp;
            bf16x8 kf1 = *(const bf16x8*)(kp + 32);
            f32x4 s = (f32x4){0.f, 0.f, 0.f, 0.f};
            s = __builtin_amdgcn_mfma_f32_16x16x32_bf16(qf0, kf0, s, 0, 0, 0);
            s = __builtin_amdgcn_mfma_f32_16x16x32_bf16(qf1, kf1, s, 0, 0, 0);
            sf[tc] = s;
        }
#pragma unroll
        for (int tc = 0; tc < 13; tc++) {
            int c = tc * 16 + l16;
            if (c < 196) {
                int kh = c / 14, kw = c - kh * 14;
#pragma unroll
                for (int j = 0; j < 4; j++) {
                    int rr = tr * 16 + quad * 4 + j;
                    if (rr > 195) rr = 195;
                    float dh = b2f(sc[(w * 2 + 0) * 448 + (quad * 4 + j) * 28 +
                                      (rr / 14 - kh + 13)]);
                    float dw = b2f(sc[(w * 2 + 1) * 448 + (quad * 4 + j) * 28 +
                                      (rr % 14 - kw + 13)]);
                    sf[tc][j] = sf[tc][j] * 0.125f + dh + dw;
                }
            } else {
#pragma unroll
                for (int j = 0; j < 4; j++) sf[tc][j] = -30000.0f;
            }
        }
        f32x4 mx = sf[0];
#pragma unroll
        for (int tc = 1; tc < 13; tc++)
#pragma unroll
            for (int j = 0; j < 4; j++) mx[j] = fmaxf(mx[j], sf[tc][j]);
        for (int off = 1; off < 16; off <<= 1)
#pragma unroll
            for (int j = 0; j < 4; j++) mx[j] = fmaxf(mx[j], __shfl_xor(mx[j], off));
        f32x4 sum = (f32x4){0.f, 0.f, 0.f, 0.f};
#pragma unroll
        for (int tc = 0; tc < 13; tc++)
#pragma unroll
            for (int j = 0; j < 4; j++) {
                float p = __expf(sf[tc][j] - mx[j]);
                sf[tc][j] = p;
                sum[j] += p;
            }
        for (int off = 1; off < 16; off <<= 1)
#pragma unroll
            for (int j = 0; j < 4; j++) sum[j] += __shfl_xor(sum[j], off);
        f32x4 linv;
#pragma unroll
        for (int j = 0; j < 4; j++) linv[j] = 1.0f / sum[j];

        f32x4 oa[4];
#pragma unroll
        for (int tn = 0; tn < 4; tn++) oa[tn] = (f32x4){0.f, 0.f, 0.f, 0.f};
#pragma unroll
        for (int tc = 0; tc < 6; tc++) {
            int c = tc * 16 + l16;
#pragma unroll
            for (int j = 0; j < 4; j++)
                Ps[(w * 16 + quad * 4 + j) * 104 + c] = f2b(sf[tc][j]);
        }
#pragma unroll
        for (int ks = 0; ks < 3; ks++) {
            bf16x8 pf = *(const bf16x8*)&Ps[(w * 16 + l16) * 104 + ks * 32 + quad * 8];
#pragma unroll
            for (int tn = 0; tn < 4; tn++) {
                bf16x8 vf = *(const bf16x8*)&Vt[(tn * 16 + l16) * 200 + ks * 32 + quad * 8];
                oa[tn] = __builtin_amdgcn_mfma_f32_16x16x32_bf16(pf, vf, oa[tn], 0, 0, 0);
            }
        }
#pragma unroll
        for (int tc = 6; tc < 13; tc++) {
            int c = tc * 16 + l16;
            if (c < 196) {
#pragma unroll
                for (int j = 0; j < 4; j++)
                    Ps[(w * 16 + quad * 4 + j) * 104 + (c - 96)] = f2b(sf[tc][j]);
            }
        }
#pragma unroll
        for (int ks = 0; ks < 3; ks++) {
            bf16x8 pf = *(const bf16x8*)&Ps[(w * 16 + l16) * 104 + ks * 32 + quad * 8];
#pragma unroll
            for (int tn = 0; tn < 4; tn++) {
                bf16x8 vf = *(const bf16x8*)&Vt[(tn * 16 + l16) * 200 + 96 + ks * 32 + quad * 8];
                oa[tn] = __builtin_amdgcn_mfma_f32_16x16x32_bf16(pf, vf, oa[tn], 0, 0, 0);
            }
        }
        for (int kk = 192; kk < 196; kk++) {
            float pj[4];
#pragma unroll
            for (int j = 0; j < 4; j++)
                pj[j] = b2f(Ps[(w * 16 + quad * 4 + j) * 104 + 96 + (kk - 192)]);
#pragma unroll
            for (int tn = 0; tn < 4; tn++) {
                float vv = b2f(Vt[(tn * 16 + l16) * 200 + kk]);
#pragma unroll
                for (int j = 0; j < 4; j++) oa[tn][j] += pj[j] * vv;
            }
        }
#pragma unroll
        for (int j = 0; j < 4; j++) {
            int rr = tr * 16 + quad * 4 + j;
            if (rr < 196) {
                int gh = whh + rr / 14, gw = www + rr % 14;
                if (gh < 64 && gw < 64) {
                    long orow = (long)img * 4096 + gh * 64 + gw - orow0;
#pragma unroll
                    for (int tn = 0; tn < 4; tn++)
                        o_out[orow * 1024 + head * 64 + tn * 16 + l16] =
                            f2b(oa[tn][j] * linv[j]);
                }
            }
        }
    }
}

// ---------------- launch ----------------
extern "C" void kernel_launch(void* const* d_in, const int* in_sizes, int n_in,
                              void* d_out, int out_size, void* d_ws, size_t ws_size,
                              hipStream_t stream) {
    const float* x = (const float*)d_in[0];
    const float* n1s = (const float*)d_in[1];
    const float* n1b = (const float*)d_in[2];
    const float* qkvW = (const float*)d_in[3];
    const float* qkvB = (const float*)d_in[4];
    const float* relH = (const float*)d_in[5];
    const float* relW = (const float*)d_in[6];
    const float* projW = (const float*)d_in[7];
    const float* projB = (const float*)d_in[8];
    const float* n2s = (const float*)d_in[9];
    const float* n2b = (const float*)d_in[10];
    const float* fc1W = (const float*)d_in[11];
    const float* fc1B = (const float*)d_in[12];
    const float* fc2W = (const float*)d_in[13];
    const float* fc2B = (const float*)d_in[14];
    float* OUT = (float*)d_out;
    char* ws = (char*)d_ws;

    if (ws_size >= 221000000ULL) {
        // ---- FULL tier (peak 220.2 MB): 11 dispatches, gemm256 pipeline ----
        ushort* T0  = (ushort*)(ws);
        ushort* TP  = (ushort*)(ws + 6291456ULL);
        ushort* TF1 = (ushort*)(ws + 8388608ULL);
        ushort* TF2 = (ushort*)(ws + 16777216ULL);
        ushort* W0  = (ushort*)(ws + 25165824ULL);
        ushort* QKV = (ushort*)(ws + 65536000ULL);
        ushort* AO  = (ushort*)(ws + 186646528ULL);
        ushort* Z   = (ushort*)(ws + 25165824ULL);
        ushort* H   = (ushort*)(ws + 58720256ULL);

        transpose_w<<<dim3(96, 32), dim3(32, 8), 0, stream>>>(qkvW, T0, 1024, 3072);
        transpose_w<<<dim3(32, 32), dim3(32, 8), 0, stream>>>(projW, TP, 1024, 1024);
        transpose_w<<<dim3(128, 32), dim3(32, 8), 0, stream>>>(fc1W, TF1, 1024, 4096);
        transpose_w<<<dim3(32, 128), dim3(32, 8), 0, stream>>>(fc2W, TF2, 4096, 1024);
        ln_part_kernel<<<19712, 256, 0, stream>>>(x, n1s, n1b, W0, 0, 100);
        gemm256<0, ushort><<<924, 512, 0, stream>>>(W0, T0, qkvB, nullptr, QKV,
                                                    19712, 3072, 1024, 12);
        attn_kernel<<<dim3(100, 16), 256, 0, stream>>>(QKV, AO, relH, relW, 0, 0L);
        gemm256<2, float><<<256, 512, 0, stream>>>(AO, TP, projB, x, OUT,
                                                   16384, 1024, 1024, 4);
        ln_kernel<<<16384, 256, 0, stream>>>(OUT, n2s, n2b, Z);
        gemm256<1, ushort><<<1024, 512, 0, stream>>>(Z, TF1, fc1B, nullptr, H,
                                                     16384, 4096, 1024, 16);
        gemm256<2, float><<<256, 512, 0, stream>>>(H, TF2, fc2B, OUT, OUT,
                                                   16384, 1024, 4096, 4);
    } else if (ws_size >= 100000000ULL) {
        // ---- MID tier (peak 99.6 MB): proven round-0 path ----
        ushort* T0  = (ushort*)(ws);
        ushort* TP  = (ushort*)(ws + 6291456ULL);
        ushort* TF1 = (ushort*)(ws + 8388608ULL);
        ushort* TF2 = (ushort*)(ws + 16777216ULL);
        ushort* AO  = (ushort*)(ws + 25165824ULL);
        ushort* W0  = (ushort*)(ws + 58720256ULL);
        ushort* QKV = (ushort*)(ws + 68943872ULL);
        ushort* Z   = (ushort*)(ws + 25165824ULL);
        ushort* H   = (ushort*)(ws + 58720256ULL);

        transpose_w<<<dim3(96, 32), dim3(32, 8), 0, stream>>>(qkvW, T0, 1024, 3072);
        transpose_w<<<dim3(32, 32), dim3(32, 8), 0, stream>>>(projW, TP, 1024, 1024);
        transpose_w<<<dim3(128, 32), dim3(32, 8), 0, stream>>>(fc1W, TF1, 1024, 4096);
        transpose_w<<<dim3(32, 128), dim3(32, 8), 0, stream>>>(fc2W, TF2, 4096, 1024);
        for (int i = 0; i < 4; i++) {
            ln_part_kernel<<<4992, 256, 0, stream>>>(x, n1s, n1b, W0, i * 25, 25);
            gemm_bt<0, ushort><<<dim3(39, 24), 256, 0, stream>>>(W0, T0, qkvB, nullptr,
                                                                 QKV, 4992, 3072, 1024);
            attn_kernel<<<dim3(25, 16), 256, 0, stream>>>(QKV, AO, relH, relW, i * 25, 0L);
        }
        gemm_bt<2, float><<<dim3(128, 8), 256, 0, stream>>>(AO, TP, projB, x, OUT,
                                                            16384, 1024, 1024);
        for (int c = 0; c < 4; c++) {
            float* xc = OUT + (long)c * 4194304;
            ln_kernel<<<4096, 256, 0, stream>>>(xc, n2s, n2b, Z);
            gemm_bt<1, ushort><<<dim3(32, 32), 256, 0, stream>>>(Z, TF1, fc1B, nullptr, H,
                                                                 4096, 4096, 1024);
            gemm_bt<2, float><<<dim3(32, 8), 256, 0, stream>>>(H, TF2, fc2B, xc, xc,
                                                               4096, 1024, 4096);
        }
    } else {
        // ---- FALLBACK (proven 31.2 MB): round-0 path ----
        ushort* T0 = (ushort*)(ws);
        ushort* W0 = (ushort*)(ws + 6291456ULL);
        ushort* W1 = (ushort*)(ws + 16515072ULL);
        ushort* W2 = (ushort*)(ws + 22806528ULL);
        ushort* F1 = (ushort*)(ws);
        ushort* F2 = (ushort*)(ws + 8388608ULL);
        ushort* Z  = (ushort*)(ws + 16777216ULL);
        ushort* H  = (ushort*)(ws + 18874368ULL);

        transpose_w<<<dim3(96, 32), dim3(32, 8), 0, stream>>>(qkvW, T0, 1024, 3072);
        for (int i = 0; i < 4; i++) {
            const float* xi = x + (long)i * 4194304;
            ln_part_kernel<<<4992, 256, 0, stream>>>(x, n1s, n1b, W0, i * 25, 25);
            for (int g = 0; g < 5; g++) {
                gemm_bt<0, ushort><<<dim3(8, 24), 256, 0, stream>>>(
                    W0 + (long)g * 980 * 1024, T0, qkvB, nullptr, W1, 1024, 3072, 1024);
                attn_kernel<<<dim3(5, 16), 256, 0, stream>>>(W1, W2, relH, relW,
                                                             i * 25 + g * 5, (long)i * 4096);
            }
            transpose_w<<<dim3(32, 32), dim3(32, 8), 0, stream>>>(projW, W1, 1024, 1024);
            gemm_bt<2, float><<<dim3(32, 8), 256, 0, stream>>>(
                W2, W1, projB, xi, OUT + (long)i * 4194304, 4096, 1024, 1024);
        }
        transpose_w<<<dim3(128, 32), dim3(32, 8), 0, stream>>>(fc1W, F1, 1024, 4096);
        transpose_w<<<dim3(32, 128), dim3(32, 8), 0, stream>>>(fc2W, F2, 4096, 1024);
        for (int c = 0; c < 16; c++) {
            float* xc = OUT + (long)c * 1048576;
            ln_kernel<<<1024, 256, 0, stream>>>(xc, n2s, n2b, Z);
            gemm_bt<1, ushort><<<dim3(8, 32), 256, 0, stream>>>(Z, F1, fc1B, nullptr, H,
                                                                1024, 4096, 1024);
            gemm_bt<2, float><<<dim3(8, 8), 256, 0, stream>>>(H, F2, fc2B, xc, xc,
                                                              1024, 1024, 4096);
        }
    }
}

// Round 3
// 901.817 us; speedup vs baseline: 1.2527x; 1.0075x over previous
//
#include <hip/hip_runtime.h>

typedef __attribute__((ext_vector_type(8))) short bf16x8;
typedef __attribute__((ext_vector_type(4))) float f32x4;
typedef __attribute__((ext_vector_type(16))) float f32x16;

__device__ __forceinline__ float b2f(ushort u) {
    union { unsigned int i; float f; } v; v.i = ((unsigned int)u) << 16; return v.f;
}
__device__ __forceinline__ ushort f2b(float f) {
    union { float f; unsigned int i; } v; v.f = f;
    unsigned int i = v.i;
    return (ushort)((i + 0x7FFFu + ((i >> 16) & 1u)) >> 16);
}
__device__ __forceinline__ void glds16(const ushort* g, ushort* l) {
    __builtin_amdgcn_global_load_lds((const __attribute__((address_space(1))) void*)g,
                                     (__attribute__((address_space(3))) void*)l, 16, 0, 0);
}
// raw barrier with compiler memory fences (no implicit vmcnt/lgkm drain)
__device__ __forceinline__ void BARX() {
    asm volatile("" ::: "memory");
    __builtin_amdgcn_s_barrier();
    asm volatile("" ::: "memory");
}

// ---- LN2: x2(fp32 rows,1024) -> y (bf16) ----
__global__ __launch_bounds__(256) void ln_kernel(const float* __restrict__ x,
                                                 const float* __restrict__ sc,
                                                 const float* __restrict__ bi,
                                                 ushort* __restrict__ y) {
    __shared__ float red[8];
    long row = blockIdx.x;
    const float* xr = x + row * 1024;
    int t = threadIdx.x;
    float4 u = *(const float4*)(xr + t * 4);
    float s = u.x + u.y + u.z + u.w;
    float q = u.x * u.x + u.y * u.y + u.z * u.z + u.w * u.w;
    for (int off = 32; off > 0; off >>= 1) {
        s += __shfl_xor(s, off);
        q += __shfl_xor(q, off);
    }
    if ((t & 63) == 0) { red[t >> 6] = s; red[4 + (t >> 6)] = q; }
    __syncthreads();
    s = red[0] + red[1] + red[2] + red[3];
    q = red[4] + red[5] + red[6] + red[7];
    float mean = s * (1.0f / 1024.0f);
    float var = q * (1.0f / 1024.0f) - mean * mean;
    float rstd = rsqrtf(fmaxf(var, 0.0f) + 1e-6f);
    int c = t * 4;
    float o0 = (u.x - mean) * rstd * sc[c + 0] + bi[c + 0];
    float o1 = (u.y - mean) * rstd * sc[c + 1] + bi[c + 1];
    float o2 = (u.z - mean) * rstd * sc[c + 2] + bi[c + 2];
    float o3 = (u.w - mean) * rstd * sc[c + 3] + bi[c + 3];
    uint2 o;
    o.x = (unsigned int)f2b(o0) | ((unsigned int)f2b(o1) << 16);
    o.y = (unsigned int)f2b(o2) | ((unsigned int)f2b(o3) << 16);
    *(uint2*)(y + row * 1024 + c) = o;
}

// ---- fused LN1 + window partition ----
__global__ __launch_bounds__(256) void ln_part_kernel(const float* __restrict__ x,
                                                      const float* __restrict__ sc,
                                                      const float* __restrict__ bi,
                                                      ushort* __restrict__ wy,
                                                      int win_base, int nvalid) {
    __shared__ float red[8];
    int wt = blockIdx.x;
    int lwin = wt / 196, rr = wt % 196;
    int t = threadIdx.x;
    int valid = 0;
    long xrow = 0;
    if (lwin < nvalid) {
        int gwin = win_base + lwin;
        int img = gwin / 25, wrem = gwin % 25;
        int gh = (wrem / 5) * 14 + rr / 14;
        int gw = (wrem % 5) * 14 + rr % 14;
        if (gh < 64 && gw < 64) {
            valid = 1;
            xrow = (long)img * 4096 + gh * 64 + gw;
        }
    }
    uint2 o; o.x = 0u; o.y = 0u;
    if (valid) {
        const float* xr = x + xrow * 1024;
        float4 u = *(const float4*)(xr + t * 4);
        float s = u.x + u.y + u.z + u.w;
        float q = u.x * u.x + u.y * u.y + u.z * u.z + u.w * u.w;
        for (int off = 32; off > 0; off >>= 1) {
            s += __shfl_xor(s, off);
            q += __shfl_xor(q, off);
        }
        if ((t & 63) == 0) { red[t >> 6] = s; red[4 + (t >> 6)] = q; }
        __syncthreads();
        s = red[0] + red[1] + red[2] + red[3];
        q = red[4] + red[5] + red[6] + red[7];
        float mean = s * (1.0f / 1024.0f);
        float var = q * (1.0f / 1024.0f) - mean * mean;
        float rstd = rsqrtf(fmaxf(var, 0.0f) + 1e-6f);
        int c = t * 4;
        float o0 = (u.x - mean) * rstd * sc[c + 0] + bi[c + 0];
        float o1 = (u.y - mean) * rstd * sc[c + 1] + bi[c + 1];
        float o2 = (u.z - mean) * rstd * sc[c + 2] + bi[c + 2];
        float o3 = (u.w - mean) * rstd * sc[c + 3] + bi[c + 3];
        o.x = (unsigned int)f2b(o0) | ((unsigned int)f2b(o1) << 16);
        o.y = (unsigned int)f2b(o2) | ((unsigned int)f2b(o3) << 16);
    }
    *(uint2*)(wy + (long)wt * 1024 + t * 4) = o;
}

// ---- transpose + cast: in fp32 (K,N) -> out bf16 (N,K) ----
__global__ void transpose_w(const float* __restrict__ in, ushort* __restrict__ out,
                            int K, int N) {
    __shared__ float tile[32][33];
    int n0 = blockIdx.x * 32, k0 = blockIdx.y * 32;
    int tx = threadIdx.x, ty = threadIdx.y;
    for (int i = 0; i < 32; i += 8)
        tile[ty + i][tx] = in[(long)(k0 + ty + i) * N + n0 + tx];
    __syncthreads();
    for (int i = 0; i < 32; i += 8)
        out[(long)(n0 + ty + i) * K + k0 + tx] = f2b(tile[tx][ty + i]);
}

// ---- legacy GEMM (m97 structure, proven) ----
template <int FLAGS, typename OT>
__global__ __launch_bounds__(256) void gemm_bt(const ushort* __restrict__ A,
                                               const ushort* __restrict__ Bt,
                                               const float* __restrict__ bias,
                                               const float* __restrict__ resid,
                                               OT* __restrict__ out,
                                               int M, int N, int K) {
    __shared__ __align__(16) ushort As[128 * 32];
    __shared__ __align__(16) ushort Bs[128 * 32];
    const int tid = threadIdx.x;
    const int lane = tid & 63, w = tid >> 6;
    const int wm = (w >> 1) * 64, wn = (w & 1) * 64;
    const int quad = lane >> 4, l16 = lane & 15;
    const int bm = blockIdx.x * 128, bn = blockIdx.y * 128;
    const int r = tid >> 2, kc = (tid & 3) * 8;
    f32x4 acc[4][4];
#pragma unroll
    for (int i = 0; i < 4; i++)
#pragma unroll
        for (int j = 0; j < 4; j++) acc[i][j] = (f32x4){0.f, 0.f, 0.f, 0.f};
    const ushort* Ag = A + (long)(bm + r) * K + kc;
    const ushort* Bg = Bt + (long)(bn + r) * K + kc;
    ushort* AsW = As + w * 512;
    ushort* BsW = Bs + w * 512;
    for (int k0 = 0; k0 < K; k0 += 32) {
        __syncthreads();
        glds16(Ag + k0, AsW);
        glds16(Ag + (long)64 * K + k0, AsW + 2048);
        glds16(Bg + k0, BsW);
        glds16(Bg + (long)64 * K + k0, BsW + 2048);
        __syncthreads();
        bf16x8 afr[4], bfr[4];
#pragma unroll
        for (int t = 0; t < 4; t++) {
            afr[t] = *(const bf16x8*)&As[(wm + t * 16 + l16) * 32 + quad * 8];
            bfr[t] = *(const bf16x8*)&Bs[(wn + t * 16 + l16) * 32 + quad * 8];
        }
#pragma unroll
        for (int tm = 0; tm < 4; tm++)
#pragma unroll
            for (int tn = 0; tn < 4; tn++)
                acc[tm][tn] = __builtin_amdgcn_mfma_f32_16x16x32_bf16(afr[tm], bfr[tn],
                                                                     acc[tm][tn], 0, 0, 0);
    }
#pragma unroll
    for (int tm = 0; tm < 4; tm++) {
#pragma unroll
        for (int j = 0; j < 4; j++) {
            int gm = bm + wm + tm * 16 + quad * 4 + j;
#pragma unroll
            for (int tn = 0; tn < 4; tn++) {
                int gn = bn + wn + tn * 16 + l16;
                float v = acc[tm][tn][j] + bias[gn];
                if (FLAGS & 1) v = 0.5f * v * (1.0f + erff(v * 0.70710678118654752f));
                if (FLAGS & 2) v += resid[(long)gm * N + gn];
                if (sizeof(OT) == 4) out[(long)gm * N + gn] = (OT)v;
                else out[(long)gm * N + gn] = (OT)f2b(v);
            }
        }
    }
}

// ============ 256x256 deep-pipelined GEMM, 32x32x16 engine ============
// BM=BN=256, BK=32, 4-deep LDS ring (128 KiB), 8 waves (2Mx4N), 512 threads.
// Per K-tile: 12 ds_read_b128 + 16 mfma_32x32x16 in two lgkm-counted halves;
// ONE barrier per K-tile. Staging via global_load_lds, counted vmcnt(8)
// (tail 8->4->0->0). Full bank swizzle swz(r) = (r&3)^((r>>2)&1) applied on
// stage-source column and read slot (rule 21) -> conflict-free 8-lane phases.
#define DSR(dst, addr, imm) \
    asm volatile("ds_read_b128 %0, %1 offset:%2" : "=&v"(dst) : "v"(addr), "n"(imm));

#define MFMA32(mf, nf, a, b) \
    acc[mf][nf] = __builtin_amdgcn_mfma_f32_32x32x16_bf16(a, b, acc[mf][nf], 0, 0, 0);

#define TILE32(bb, ts, STG, VM) do {                                                     \
    bf16x8 b00, b10, a00, a10, a20, a30, b01, b11, a01, a11, a21, a31;                   \
    DSR(b00, b_k0, (bb) * 16384 + 0)                                                     \
    DSR(b10, b_k0, (bb) * 16384 + 2048)                                                  \
    DSR(a00, a_k0, (bb) * 16384 + 0)                                                     \
    DSR(a10, a_k0, (bb) * 16384 + 2048)                                                  \
    DSR(a20, a_k0, (bb) * 16384 + 4096)                                                  \
    DSR(a30, a_k0, (bb) * 16384 + 6144)                                                  \
    DSR(b01, b_k1, (bb) * 16384 + 0)                                                     \
    DSR(b11, b_k1, (bb) * 16384 + 2048)                                                  \
    DSR(a01, a_k1, (bb) * 16384 + 0)                                                     \
    DSR(a11, a_k1, (bb) * 16384 + 2048)                                                  \
    DSR(a21, a_k1, (bb) * 16384 + 4096)                                                  \
    DSR(a31, a_k1, (bb) * 16384 + 6144)                                                  \
    if (STG) {                                                                           \
        glds16(Ag + (long)(ts) * 32, &As[((bb) + 3) & 3][sdst]);                         \
        glds16(Ag2 + (long)(ts) * 32, &As[((bb) + 3) & 3][sdst + 4096]);                 \
        glds16(Bg + (long)(ts) * 32, &Bs[((bb) + 3) & 3][sdst]);                         \
        glds16(Bg2 + (long)(ts) * 32, &Bs[((bb) + 3) & 3][sdst + 4096]);                 \
    }                                                                                    \
    __builtin_amdgcn_sched_barrier(0);                                                   \
    asm volatile("s_waitcnt lgkmcnt(6)" ::: "memory");                                   \
    __builtin_amdgcn_sched_barrier(0);                                                   \
    __builtin_amdgcn_s_setprio(1);                                                       \
    MFMA32(0, 0, a00, b00) MFMA32(0, 1, a00, b10)                                        \
    MFMA32(1, 0, a10, b00) MFMA32(1, 1, a10, b10)                                        \
    MFMA32(2, 0, a20, b00) MFMA32(2, 1, a20, b10)                                        \
    MFMA32(3, 0, a30, b00) MFMA32(3, 1, a30, b10)                                        \
    __builtin_amdgcn_s_setprio(0);                                                       \
    asm volatile("s_waitcnt lgkmcnt(0)" ::: "memory");                                   \
    __builtin_amdgcn_sched_barrier(0);                                                   \
    __builtin_amdgcn_s_setprio(1);                                                       \
    MFMA32(0, 0, a01, b01) MFMA32(0, 1, a01, b11)                                        \
    MFMA32(1, 0, a11, b01) MFMA32(1, 1, a11, b11)                                        \
    MFMA32(2, 0, a21, b01) MFMA32(2, 1, a21, b11)                                        \
    MFMA32(3, 0, a31, b01) MFMA32(3, 1, a31, b11)                                        \
    __builtin_amdgcn_s_setprio(0);                                                       \
    __builtin_amdgcn_sched_barrier(0);                                                   \
    asm volatile("s_waitcnt " VM ::: "memory");                                          \
    BARX();                                                                              \
} while (0)

template <int FLAGS, typename OT>
__global__ __launch_bounds__(512, 2) void gemm256(const ushort* __restrict__ A,
                                                  const ushort* __restrict__ Bt,
                                                  const float* __restrict__ bias,
                                                  const float* __restrict__ resid,
                                                  OT* __restrict__ out,
                                                  int M, int N, int K, int nbn) {
    __shared__ __align__(64) ushort As[4][8192];   // 4 x (256 rows x 32 halfs) = 64 KB
    __shared__ __align__(64) ushort Bs[4][8192];   // 64 KB
    // bijective XCD swizzle (m204)
    const int nwg = gridDim.x;
    const int orig = blockIdx.x;
    const int q8 = nwg >> 3, r8 = nwg & 7;
    const int xcd = orig & 7, sub = orig >> 3;
    const int wgid = (xcd < r8 ? xcd * (q8 + 1) : r8 * (q8 + 1) + (xcd - r8) * q8) + sub;
    const int bm = (wgid / nbn) * 256, bn = (wgid % nbn) * 256;

    const int tid = threadIdx.x;
    const int lane = tid & 63, w = tid >> 6;
    const int l31 = lane & 31, hi = lane >> 5;
    const int wm = (w >> 2) * 128, wn = (w & 3) * 64;

    // staging: per glds a wave writes 16 rows x 64B linearly into LDS; the source
    // column slot is pre-swizzled with swz(r)=(r&3)^((r>>2)&1) (rule 21).
    const int r_st = w * 16 + (lane >> 2);                     // 0..127
    const int c_st = (((lane & 3) ^ ((lane >> 2) & 3) ^ ((lane >> 4) & 1)) << 3);
    const ushort* Ag = A + (long)(bm + r_st) * K + c_st;
    const ushort* Ag2 = Ag + (long)128 * K;
    const ushort* Bg = Bt + (long)(bn + r_st) * K + c_st;
    const ushort* Bg2 = Bg + (long)128 * K;
    const int sdst = w * 512;                                  // halfs

    // read addressing (32x32x16 frags): row = l31, k-span = hi*8 (+16 for kh1).
    // physical 16B slot = logical(kh*2+hi) ^ swz(row); swz depends only on lane bits.
    const int swz = (lane & 3) ^ ((lane >> 2) & 1);
    const int s0 = swz & 1, s1 = swz >> 1;
    const int slot_k0 = (((0 ^ s1) << 1) | (hi ^ s0)) << 4;    // bytes
    const int slot_k1 = (((1 ^ s1) << 1) | (hi ^ s0)) << 4;
    const unsigned As0 =
        (unsigned)(size_t)(__attribute__((address_space(3))) ushort*)&As[0][0];
    const unsigned Bs0 =
        (unsigned)(size_t)(__attribute__((address_space(3))) ushort*)&Bs[0][0];
    const unsigned a_k0 = As0 + (unsigned)((wm + l31) * 64 + slot_k0);
    const unsigned a_k1 = As0 + (unsigned)((wm + l31) * 64 + slot_k1);
    const unsigned b_k0 = Bs0 + (unsigned)((wn + l31) * 64 + slot_k0);
    const unsigned b_k1 = Bs0 + (unsigned)((wn + l31) * 64 + slot_k1);

    f32x16 acc[4][2];
#pragma unroll
    for (int i = 0; i < 4; i++)
#pragma unroll
        for (int j = 0; j < 2; j++)
#pragma unroll
            for (int e = 0; e < 16; e++) acc[i][j][e] = 0.f;

    // prologue: stage K-tiles 0,1,2 into buffers 0,1,2 (12 loads), keep 2 in flight
    glds16(Ag, &As[0][sdst]);       glds16(Ag2, &As[0][sdst + 4096]);
    glds16(Bg, &Bs[0][sdst]);       glds16(Bg2, &Bs[0][sdst + 4096]);
    glds16(Ag + 32, &As[1][sdst]);  glds16(Ag2 + 32, &As[1][sdst + 4096]);
    glds16(Bg + 32, &Bs[1][sdst]);  glds16(Bg2 + 32, &Bs[1][sdst + 4096]);
    glds16(Ag + 64, &As[2][sdst]);  glds16(Ag2 + 64, &As[2][sdst + 4096]);
    glds16(Bg + 64, &Bs[2][sdst]);  glds16(Bg2 + 64, &Bs[2][sdst + 4096]);
    __builtin_amdgcn_sched_barrier(0);
    asm volatile("s_waitcnt vmcnt(8)" ::: "memory");  // tile 0 landed
    BARX();

    const int nt = K >> 5;  // 32 (K=1024) or 128 (K=4096); divisible by 4, >= 8
    for (int t = 0; t < nt - 4; t += 4) {
        TILE32(0, t + 3, 1, "vmcnt(8)");
        TILE32(1, t + 4, 1, "vmcnt(8)");
        TILE32(2, t + 5, 1, "vmcnt(8)");
        TILE32(3, t + 6, 1, "vmcnt(8)");
    }
    // peeled tail: tiles nt-4..nt-1; stage last tile (nt-1); drain 8 -> 4 -> 0
    TILE32(0, nt - 1, 1, "vmcnt(8)");
    TILE32(1, 0, 0, "vmcnt(4)");
    TILE32(2, 0, 0, "vmcnt(0)");
    TILE32(3, 0, 0, "vmcnt(0)");

    // epilogue: C frag layout col=lane&31, row=(reg&3)+8*(reg>>2)+4*hi  [m74/m101]
#pragma unroll
    for (int mf = 0; mf < 4; mf++) {
#pragma unroll
        for (int nf = 0; nf < 2; nf++) {
            const int gn = bn + wn + nf * 32 + l31;
#pragma unroll
            for (int q = 0; q < 4; q++) {
#pragma unroll
                for (int j = 0; j < 4; j++) {
                    const int gm = bm + wm + mf * 32 + q * 8 + j + 4 * hi;
                    const long ro = (long)gm * N;
                    float v = acc[mf][nf][q * 4 + j] + bias[gn];
                    if (FLAGS & 1) v = 0.5f * v * (1.0f + erff(v * 0.70710678118654752f));
                    if (FLAGS & 2) v += resid[ro + gn];
                    if (sizeof(OT) == 4) out[ro + gn] = (OT)v;
                    else out[ro + gn] = (OT)f2b(v);
                }
            }
        }
    }
}

// ---- attention per (window, head): rel-pos via MFMA, 46 KB LDS ----
__global__ __launch_bounds__(256) void attn_kernel(const ushort* __restrict__ qkv,
                                                   ushort* __restrict__ o_out,
                                                   const float* __restrict__ relH,
                                                   const float* __restrict__ relW,
                                                   int win0, long orow0) {
    __shared__ __align__(16) ushort Vt[64 * 200];
    __shared__ __align__(16) ushort Ps[64 * 104];
    __shared__ __align__(16) ushort sc[8 * 448];
    const int head = blockIdx.y;
    const long qbase = (long)blockIdx.x * 196 * 3072 + head * 64;
    const int gwin = win0 + blockIdx.x;
    const int img = gwin / 25, wrem = gwin % 25;
    const int whh = (wrem / 5) * 14, www = (wrem % 5) * 14;
    const int tid = threadIdx.x, lane = tid & 63, w = tid >> 6;
    const int quad = lane >> 4, l16 = lane & 15;

    for (int idx = tid; idx < 196 * 64; idx += 256) {
        int k = idx >> 6, d = idx & 63;
        Vt[d * 200 + k] = qkv[qbase + 2048 + (long)k * 3072 + d];
    }
    __syncthreads();

    bf16x8 bH[2][2], bW[2][2];
#pragma unroll
    for (int nt = 0; nt < 2; nt++) {
        int n = nt * 16 + l16;
#pragma unroll
        for (int kt = 0; kt < 2; kt++) {
            bf16x8 rh = (bf16x8){0, 0, 0, 0, 0, 0, 0, 0};
            bf16x8 rw = (bf16x8){0, 0, 0, 0, 0, 0, 0, 0};
            if (n < 27) {
                const float* ph = relH + n * 64 + kt * 32 + quad * 8;
                const float* pw = relW + n * 64 + kt * 32 + quad * 8;
#pragma unroll
                for (int e = 0; e < 8; e++) {
                    rh[e] = (short)f2b(ph[e]);
                    rw[e] = (short)f2b(pw[e]);
                }
            }
            bH[nt][kt] = rh;
            bW[nt][kt] = rw;
        }
    }

    for (int tr = w; tr < 13; tr += 4) {
        int qrow = tr * 16 + l16;
        if (qrow > 195) qrow = 195;
        bf16x8 qf0 = *(const bf16x8*)(qkv + qbase + (long)qrow * 3072 + quad * 8);
        bf16x8 qf1 = *(const bf16x8*)(qkv + qbase + (long)qrow * 3072 + 32 + quad * 8);

#pragma unroll
        for (int tab = 0; tab < 2; tab++) {
#pragma unroll
            for (int nt = 0; nt < 2; nt++) {
                f32x4 a = (f32x4){0.f, 0.f, 0.f, 0.f};
                a = __builtin_amdgcn_mfma_f32_16x16x32_bf16(qf0, tab ? bW[nt][0] : bH[nt][0],
                                                            a, 0, 0, 0);
                a = __builtin_amdgcn_mfma_f32_16x16x32_bf16(qf1, tab ? bW[nt][1] : bH[nt][1],
                                                            a, 0, 0, 0);
                int col = nt * 16 + l16;
                if (col < 27) {
#pragma unroll
                    for (int j = 0; j < 4; j++)
                        sc[(w * 2 + tab) * 448 + (quad * 4 + j) * 28 + col] = f2b(a[j]);
                }
            }
        }

        f32x4 sf[13];
#pragma unroll
        for (int tc = 0; tc < 13; tc++) {
            int krow = tc * 16 + l16;
            if (krow > 195) krow = 195;
            const ushort* kp = qkv + qbase + 1024 + (long)krow * 3072 + quad * 8;
            bf16x8 kf0 = *(const bf16x8*)kp;
            bf16x8 kf1 = *(const bf16x8*)(kp + 32);
            f32x4 s = (f32x4){0.f, 0.f, 0.f, 0.f};
            s = __builtin_amdgcn_mfma_f32_16x16x32_bf16(qf0, kf0, s, 0, 0, 0);
            s = __builtin_amdgcn_mfma_f32_16x16x32_bf16(qf1, kf1, s, 0, 0, 0);
            sf[tc] = s;
        }
#pragma unroll
        for (int tc = 0; tc < 13; tc++) {
            int c = tc * 16 + l16;
            if (c < 196) {
                int kh = c / 14, kw = c - kh * 14;
#pragma unroll
                for (int j = 0; j < 4; j++) {
                    int rr = tr * 16 + quad * 4 + j;
                    if (rr > 195) rr = 195;
                    float dh = b2f(sc[(w * 2 + 0) * 448 + (quad * 4 + j) * 28 +
                                      (rr / 14 - kh + 13)]);
                    float dw = b2f(sc[(w * 2 + 1) * 448 + (quad * 4 + j) * 28 +
                                      (rr % 14 - kw + 13)]);
                    sf[tc][j] = sf[tc][j] * 0.125f + dh + dw;
                }
            } else {
#pragma unroll
                for (int j = 0; j < 4; j++) sf[tc][j] = -30000.0f;
            }
        }
        f32x4 mx = sf[0];
#pragma unroll
        for (int tc = 1; tc < 13; tc++)
#pragma unroll
            for (int j = 0; j < 4; j++) mx[j] = fmaxf(mx[j], sf[tc][j]);
        for (int off = 1; off < 16; off <<= 1)
#pragma unroll
            for (int j = 0; j < 4; j++) mx[j] = fmaxf(mx[j], __shfl_xor(mx[j], off));
        f32x4 sum = (f32x4){0.f, 0.f, 0.f, 0.f};
#pragma unroll
        for (int tc = 0; tc < 13; tc++)
#pragma unroll
            for (int j = 0; j < 4; j++) {
                float p = __expf(sf[tc][j] - mx[j]);
                sf[tc][j] = p;
                sum[j] += p;
            }
        for (int off = 1; off < 16; off <<= 1)
#pragma unroll
            for (int j = 0; j < 4; j++) sum[j] += __shfl_xor(sum[j], off);
        f32x4 linv;
#pragma unroll
        for (int j = 0; j < 4; j++) linv[j] = 1.0f / sum[j];

        f32x4 oa[4];
#pragma unroll
        for (int tn = 0; tn < 4; tn++) oa[tn] = (f32x4){0.f, 0.f, 0.f, 0.f};
#pragma unroll
        for (int tc = 0; tc < 6; tc++) {
            int c = tc * 16 + l16;
#pragma unroll
            for (int j = 0; j < 4; j++)
                Ps[(w * 16 + quad * 4 + j) * 104 + c] = f2b(sf[tc][j]);
        }
#pragma unroll
        for (int ks = 0; ks < 3; ks++) {
            bf16x8 pf = *(const bf16x8*)&Ps[(w * 16 + l16) * 104 + ks * 32 + quad * 8];
#pragma unroll
            for (int tn = 0; tn < 4; tn++) {
                bf16x8 vf = *(const bf16x8*)&Vt[(tn * 16 + l16) * 200 + ks * 32 + quad * 8];
                oa[tn] = __builtin_amdgcn_mfma_f32_16x16x32_bf16(pf, vf, oa[tn], 0, 0, 0);
            }
        }
#pragma unroll
        for (int tc = 6; tc < 13; tc++) {
            int c = tc * 16 + l16;
            if (c < 196) {
#pragma unroll
                for (int j = 0; j < 4; j++)
                    Ps[(w * 16 + quad * 4 + j) * 104 + (c - 96)] = f2b(sf[tc][j]);
            }
        }
#pragma unroll
        for (int ks = 0; ks < 3; ks++) {
            bf16x8 pf = *(const bf16x8*)&Ps[(w * 16 + l16) * 104 + ks * 32 + quad * 8];
#pragma unroll
            for (int tn = 0; tn < 4; tn++) {
                bf16x8 vf = *(const bf16x8*)&Vt[(tn * 16 + l16) * 200 + 96 + ks * 32 + quad * 8];
                oa[tn] = __builtin_amdgcn_mfma_f32_16x16x32_bf16(pf, vf, oa[tn], 0, 0, 0);
            }
        }
        for (int kk = 192; kk < 196; kk++) {
            float pj[4];
#pragma unroll
            for (int j = 0; j < 4; j++)
                pj[j] = b2f(Ps[(w * 16 + quad * 4 + j) * 104 + 96 + (kk - 192)]);
#pragma unroll
            for (int tn = 0; tn < 4; tn++) {
                float vv = b2f(Vt[(tn * 16 + l16) * 200 + kk]);
#pragma unroll
                for (int j = 0; j < 4; j++) oa[tn][j] += pj[j] * vv;
            }
        }
#pragma unroll
        for (int j = 0; j < 4; j++) {
            int rr = tr * 16 + quad * 4 + j;
            if (rr < 196) {
                int gh = whh + rr / 14, gw = www + rr % 14;
                if (gh < 64 && gw < 64) {
                    long orow = (long)img * 4096 + gh * 64 + gw - orow0;
#pragma unroll
                    for (int tn = 0; tn < 4; tn++)
                        o_out[orow * 1024 + head * 64 + tn * 16 + l16] =
                            f2b(oa[tn][j] * linv[j]);
                }
            }
        }
    }
}

// ---------------- launch ----------------
extern "C" void kernel_launch(void* const* d_in, const int* in_sizes, int n_in,
                              void* d_out, int out_size, void* d_ws, size_t ws_size,
                              hipStream_t stream) {
    const float* x = (const float*)d_in[0];
    const float* n1s = (const float*)d_in[1];
    const float* n1b = (const float*)d_in[2];
    const float* qkvW = (const float*)d_in[3];
    const float* qkvB = (const float*)d_in[4];
    const float* relH = (const float*)d_in[5];
    const float* relW = (const float*)d_in[6];
    const float* projW = (const float*)d_in[7];
    const float* projB = (const float*)d_in[8];
    const float* n2s = (const float*)d_in[9];
    const float* n2b = (const float*)d_in[10];
    const float* fc1W = (const float*)d_in[11];
    const float* fc1B = (const float*)d_in[12];
    const float* fc2W = (const float*)d_in[13];
    const float* fc2B = (const float*)d_in[14];
    float* OUT = (float*)d_out;
    char* ws = (char*)d_ws;

    if (ws_size >= 221000000ULL) {
        // ---- FULL tier (peak 220.2 MB): 11 dispatches, gemm256 pipeline ----
        ushort* T0  = (ushort*)(ws);
        ushort* TP  = (ushort*)(ws + 6291456ULL);
        ushort* TF1 = (ushort*)(ws + 8388608ULL);
        ushort* TF2 = (ushort*)(ws + 16777216ULL);
        ushort* W0  = (ushort*)(ws + 25165824ULL);
        ushort* QKV = (ushort*)(ws + 65536000ULL);
        ushort* AO  = (ushort*)(ws + 186646528ULL);
        ushort* Z   = (ushort*)(ws + 25165824ULL);
        ushort* H   = (ushort*)(ws + 58720256ULL);

        transpose_w<<<dim3(96, 32), dim3(32, 8), 0, stream>>>(qkvW, T0, 1024, 3072);
        transpose_w<<<dim3(32, 32), dim3(32, 8), 0, stream>>>(projW, TP, 1024, 1024);
        transpose_w<<<dim3(128, 32), dim3(32, 8), 0, stream>>>(fc1W, TF1, 1024, 4096);
        transpose_w<<<dim3(32, 128), dim3(32, 8), 0, stream>>>(fc2W, TF2, 4096, 1024);
        ln_part_kernel<<<19712, 256, 0, stream>>>(x, n1s, n1b, W0, 0, 100);
        gemm256<0, ushort><<<924, 512, 0, stream>>>(W0, T0, qkvB, nullptr, QKV,
                                                    19712, 3072, 1024, 12);
        attn_kernel<<<dim3(100, 16), 256, 0, stream>>>(QKV, AO, relH, relW, 0, 0L);
        gemm256<2, float><<<256, 512, 0, stream>>>(AO, TP, projB, x, OUT,
                                                   16384, 1024, 1024, 4);
        ln_kernel<<<16384, 256, 0, stream>>>(OUT, n2s, n2b, Z);
        gemm256<1, ushort><<<1024, 512, 0, stream>>>(Z, TF1, fc1B, nullptr, H,
                                                     16384, 4096, 1024, 16);
        gemm256<2, float><<<256, 512, 0, stream>>>(H, TF2, fc2B, OUT, OUT,
                                                   16384, 1024, 4096, 4);
    } else if (ws_size >= 100000000ULL) {
        // ---- MID tier (peak 99.6 MB): proven round-0 path ----
        ushort* T0  = (ushort*)(ws);
        ushort* TP  = (ushort*)(ws + 6291456ULL);
        ushort* TF1 = (ushort*)(ws + 8388608ULL);
        ushort* TF2 = (ushort*)(ws + 16777216ULL);
        ushort* AO  = (ushort*)(ws + 25165824ULL);
        ushort* W0  = (ushort*)(ws + 58720256ULL);
        ushort* QKV = (ushort*)(ws + 68943872ULL);
        ushort* Z   = (ushort*)(ws + 25165824ULL);
        ushort* H   = (ushort*)(ws + 58720256ULL);

        transpose_w<<<dim3(96, 32), dim3(32, 8), 0, stream>>>(qkvW, T0, 1024, 3072);
        transpose_w<<<dim3(32, 32), dim3(32, 8), 0, stream>>>(projW, TP, 1024, 1024);
        transpose_w<<<dim3(128, 32), dim3(32, 8), 0, stream>>>(fc1W, TF1, 1024, 4096);
        transpose_w<<<dim3(32, 128), dim3(32, 8), 0, stream>>>(fc2W, TF2, 4096, 1024);
        for (int i = 0; i < 4; i++) {
            ln_part_kernel<<<4992, 256, 0, stream>>>(x, n1s, n1b, W0, i * 25, 25);
            gemm_bt<0, ushort><<<dim3(39, 24), 256, 0, stream>>>(W0, T0, qkvB, nullptr,
                                                                 QKV, 4992, 3072, 1024);
            attn_kernel<<<dim3(25, 16), 256, 0, stream>>>(QKV, AO, relH, relW, i * 25, 0L);
        }
        gemm_bt<2, float><<<dim3(128, 8), 256, 0, stream>>>(AO, TP, projB, x, OUT,
                                                            16384, 1024, 1024);
        for (int c = 0; c < 4; c++) {
            float* xc = OUT + (long)c * 4194304;
            ln_kernel<<<4096, 256, 0, stream>>>(xc, n2s, n2b, Z);
            gemm_bt<1, ushort><<<dim3(32, 32), 256, 0, stream>>>(Z, TF1, fc1B, nullptr, H,
                                                                 4096, 4096, 1024);
            gemm_bt<2, float><<<dim3(32, 8), 256, 0, stream>>>(H, TF2, fc2B, xc, xc,
                                                               4096, 1024, 4096);
        }
    } else {
        // ---- FALLBACK (proven 31.2 MB): round-0 path ----
        ushort* T0 = (ushort*)(ws);
        ushort* W0 = (ushort*)(ws + 6291456ULL);
        ushort* W1 = (ushort*)(ws + 16515072ULL);
        ushort* W2 = (ushort*)(ws + 22806528ULL);
        ushort* F1 = (ushort*)(ws);
        ushort* F2 = (ushort*)(ws + 8388608ULL);
        ushort* Z  = (ushort*)(ws + 16777216ULL);
        ushort* H  = (ushort*)(ws + 18874368ULL);

        transpose_w<<<dim3(96, 32), dim3(32, 8), 0, stream>>>(qkvW, T0, 1024, 3072);
        for (int i = 0; i < 4; i++) {
            const float* xi = x + (long)i * 4194304;
            ln_part_kernel<<<4992, 256, 0, stream>>>(x, n1s, n1b, W0, i * 25, 25);
            for (int g = 0; g < 5; g++) {
                gemm_bt<0, ushort><<<dim3(8, 24), 256, 0, stream>>>(
                    W0 + (long)g * 980 * 1024, T0, qkvB, nullptr, W1, 1024, 3072, 1024);
                attn_kernel<<<dim3(5, 16), 256, 0, stream>>>(W1, W2, relH, relW,
                                                             i * 25 + g * 5, (long)i * 4096);
            }
            transpose_w<<<dim3(32, 32), dim3(32, 8), 0, stream>>>(projW, W1, 1024, 1024);
            gemm_bt<2, float><<<dim3(32, 8), 256, 0, stream>>>(
                W2, W1, projB, xi, OUT + (long)i * 4194304, 4096, 1024, 1024);
        }
        transpose_w<<<dim3(128, 32), dim3(32, 8), 0, stream>>>(fc1W, F1, 1024, 4096);
        transpose_w<<<dim3(32, 128), dim3(32, 8), 0, stream>>>(fc2W, F2, 4096, 1024);
        for (int c = 0; c < 16; c++) {
            float* xc = OUT + (long)c * 1048576;
            ln_kernel<<<1024, 256, 0, stream>>>(xc, n2s, n2b, Z);
            gemm_bt<1, ushort><<<dim3(8, 32), 256, 0, stream>>>(Z, F1, fc1B, nullptr, H,
                                                                1024, 4096, 1024);
            gemm_bt<2, float><<<dim3(8, 8), 256, 0, stream>>>(H, F2, fc2B, xc, xc,
                                                              1024, 1024, 4096);
        }
    }
}